// Round 1
// baseline (1033.387 us; speedup 1.0000x reference)
//
#include <hip/hip_runtime.h>
#include <math.h>

#define TOK 65536
#define DIN 256
#define EDIM 512
#define KCB 2048

// workspace layout (float offsets)
#define OFF_MP   0u                       // M' [2048*256]
#define OFF_CP   (OFF_MP + KCB*DIN)       // c' [2048]
#define OFF_Q    (OFF_CP + KCB)           // Q  [2048*256]
#define OFF_W2T  (OFF_Q + KCB*DIN)        // W2T [512*256]
#define OFF_U    (OFF_W2T + EDIM*DIN)     // u [512]
#define OFF_CQ   (OFF_U + EDIM)           // cQ [256]
#define OFF_IDX  (OFF_CQ + DIN)           // idx [65536] ints

// zero loss scalar + usage region of d_out (harness poisons with 0xAA)
__global__ void zero_out_kernel(float* __restrict__ out) {
    int i = blockIdx.x * 256 + threadIdx.x;
    if (i == 0) out[0] = 0.0f;
    if (i < KCB) out[1 + TOK * DIN + i] = 0.0f;
}

// blocks 0..511: e=blockIdx -> W2T[e][o] and u[e]
// blocks 512..767: o=blockIdx-512 -> cQ[o]
__global__ void prep1_kernel(const float* __restrict__ W1, const float* __restrict__ W2,
                             const float* __restrict__ bn1_beta, const float* __restrict__ bn2_gamma,
                             const float* __restrict__ bn2_beta, const float* __restrict__ b2,
                             float* __restrict__ W2T, float* __restrict__ u, float* __restrict__ cQ) {
    __shared__ float red[256];
    const int b = blockIdx.x, t = threadIdx.x;
    const float s = 1.0f / sqrtf(1.0f + 1e-5f);
    if (b < EDIM) {
        int e = b;
        // W2T[e][o] = g2[e]*s * W2[o][e]
        W2T[e * DIN + t] = bn2_gamma[e] * s * W2[t * EDIM + e];
        // u[e] = sum_j beta1[j] * W1[e][j]
        float v = bn1_beta[t] * W1[e * DIN + t];
        red[t] = v; __syncthreads();
        for (int off = 128; off; off >>= 1) { if (t < off) red[t] += red[t + off]; __syncthreads(); }
        if (t == 0) u[e] = red[0];
    } else {
        int o = b - EDIM;
        float v = bn2_beta[t] * W2[o * EDIM + t] + bn2_beta[t + 256] * W2[o * EDIM + t + 256];
        red[t] = v; __syncthreads();
        for (int off = 128; off; off >>= 1) { if (t < off) red[t] += red[t + off]; __syncthreads(); }
        if (t == 0) cQ[o] = b2[o] + red[0];
    }
}

// per block: 4 codebook rows. M'[k][j] = g1[j]*s*sum_e E[k][e]*W1[e][j];  Q[k][j] = sum_e E[k][e]*W2T[e][j] + cQ[j]
__global__ __launch_bounds__(256) void prep2_kernel(const float* __restrict__ E, const float* __restrict__ W1,
                                                    const float* __restrict__ W2T, const float* __restrict__ bn1_gamma,
                                                    const float* __restrict__ cQ,
                                                    float* __restrict__ Mp, float* __restrict__ Q) {
    __shared__ float Elds[EDIM * 4]; // [e][kk]
    const int k0 = blockIdx.x * 4, t = threadIdx.x;
    const float4* src = (const float4*)(E + (size_t)k0 * EDIM);
    for (int i = t; i < 512; i += 256) {
        float4 v = src[i];
        int kk = i >> 7;
        int e = (i & 127) << 2;
        Elds[(e + 0) * 4 + kk] = v.x; Elds[(e + 1) * 4 + kk] = v.y;
        Elds[(e + 2) * 4 + kk] = v.z; Elds[(e + 3) * 4 + kk] = v.w;
    }
    __syncthreads();
    float m0 = 0, m1 = 0, m2 = 0, m3 = 0, q0 = 0, q1 = 0, q2 = 0, q3 = 0;
    for (int e = 0; e < EDIM; e++) {
        float4 ev = *(const float4*)&Elds[e * 4];
        float w1 = W1[e * DIN + t];
        float w2 = W2T[e * DIN + t];
        m0 += ev.x * w1; m1 += ev.y * w1; m2 += ev.z * w1; m3 += ev.w * w1;
        q0 += ev.x * w2; q1 += ev.y * w2; q2 += ev.z * w2; q3 += ev.w * w2;
    }
    const float s = 1.0f / sqrtf(1.0f + 1e-5f);
    const float gs = bn1_gamma[t] * s;
    const float cq = cQ[t];
    Mp[(size_t)(k0 + 0) * DIN + t] = gs * m0;
    Mp[(size_t)(k0 + 1) * DIN + t] = gs * m1;
    Mp[(size_t)(k0 + 2) * DIN + t] = gs * m2;
    Mp[(size_t)(k0 + 3) * DIN + t] = gs * m3;
    Q[(size_t)(k0 + 0) * DIN + t] = q0 + cq;
    Q[(size_t)(k0 + 1) * DIN + t] = q1 + cq;
    Q[(size_t)(k0 + 2) * DIN + t] = q2 + cq;
    Q[(size_t)(k0 + 3) * DIN + t] = q3 + cq;
}

// c'[k] = sum_e E[k][e]*(b1[e]+u[e]) - 0.5*sum_e E[k][e]^2
__global__ void prep3_kernel(const float* __restrict__ E, const float* __restrict__ b1,
                             const float* __restrict__ u, float* __restrict__ cp) {
    int k = blockIdx.x * 256 + threadIdx.x;
    const float4* er = (const float4*)(E + (size_t)k * EDIM);
    float sa = 0.0f, sb = 0.0f;
    for (int i = 0; i < 128; i++) {
        float4 ev = er[i];
        int e = i * 4;
        sa += ev.x * (b1[e] + u[e]) + ev.y * (b1[e + 1] + u[e + 1])
            + ev.z * (b1[e + 2] + u[e + 2]) + ev.w * (b1[e + 3] + u[e + 3]);
        sb += ev.x * ev.x + ev.y * ev.y + ev.z * ev.z + ev.w * ev.w;
    }
    cp[k] = sa - 0.5f * sb;
}

// the big one: scores = flat @ M'^T + c', fused argmax over all 2048 codes.
// block: 128 rows x all codes (16 chunks of 128). 256 threads, 8x8 register tile.
__global__ __launch_bounds__(256) void score_argmax_kernel(const float* __restrict__ flat,
                                                           const float* __restrict__ Mp,
                                                           const float* __restrict__ cp,
                                                           int* __restrict__ idxOut) {
    __shared__ float As[8 * 128];  // [k][m]
    __shared__ float Bs[8 * 128];  // [k][n]
    __shared__ float rv[128 * 16];
    __shared__ int   ri[128 * 16];
    const int t = threadIdx.x;
    const int ty = t >> 4, tx = t & 15;
    const int r0 = blockIdx.x * 128;
    const int sm = t >> 1;          // staging row 0..127
    const int sk = (t & 1) * 4;     // staging k sub-offset

    float bestv[8];
    int besti[8];
#pragma unroll
    for (int i = 0; i < 8; i++) { bestv[i] = -3.4e38f; besti[i] = 0; }

    const float* Ab = flat + (size_t)(r0 + sm) * DIN + sk;

    for (int ch = 0; ch < 16; ch++) {
        float acc[8][8];
#pragma unroll
        for (int i = 0; i < 8; i++)
#pragma unroll
            for (int j = 0; j < 8; j++) acc[i][j] = 0.0f;

        const float* Bb = Mp + (size_t)(ch * 128 + sm) * DIN + sk;
        float4 av = *(const float4*)(Ab);
        float4 bv = *(const float4*)(Bb);

        for (int ks = 0; ks < 32; ks++) {
            __syncthreads();
            As[(sk + 0) * 128 + sm] = av.x; As[(sk + 1) * 128 + sm] = av.y;
            As[(sk + 2) * 128 + sm] = av.z; As[(sk + 3) * 128 + sm] = av.w;
            Bs[(sk + 0) * 128 + sm] = bv.x; Bs[(sk + 1) * 128 + sm] = bv.y;
            Bs[(sk + 2) * 128 + sm] = bv.z; Bs[(sk + 3) * 128 + sm] = bv.w;
            __syncthreads();
            if (ks < 31) {  // prefetch next stage while computing
                av = *(const float4*)(Ab + (ks + 1) * 8);
                bv = *(const float4*)(Bb + (ks + 1) * 8);
            }
#pragma unroll
            for (int k = 0; k < 8; k++) {
                float4 a0 = *(const float4*)&As[k * 128 + ty * 8];
                float4 a1 = *(const float4*)&As[k * 128 + ty * 8 + 4];
                float4 b0 = *(const float4*)&Bs[k * 128 + tx * 8];
                float4 b1 = *(const float4*)&Bs[k * 128 + tx * 8 + 4];
                float a[8] = {a0.x, a0.y, a0.z, a0.w, a1.x, a1.y, a1.z, a1.w};
                float b[8] = {b0.x, b0.y, b0.z, b0.w, b1.x, b1.y, b1.z, b1.w};
#pragma unroll
                for (int i = 0; i < 8; i++)
#pragma unroll
                    for (int j = 0; j < 8; j++) acc[i][j] += a[i] * b[j];
            }
        }
        // chunk epilogue: add c', update running argmax (strict > keeps lowest index)
#pragma unroll
        for (int j = 0; j < 8; j++) {
            int code = ch * 128 + tx * 8 + j;
            float cj = cp[code];
#pragma unroll
            for (int i = 0; i < 8; i++) {
                float v = acc[i][j] + cj;
                if (v > bestv[i]) { bestv[i] = v; besti[i] = code; }
            }
        }
    }
    // cross-thread (tx) reduce per row, tie -> lower index
#pragma unroll
    for (int i = 0; i < 8; i++) {
        rv[(ty * 8 + i) * 16 + tx] = bestv[i];
        ri[(ty * 8 + i) * 16 + tx] = besti[i];
    }
    __syncthreads();
    if (t < 128) {
        float bv = rv[t * 16];
        int bi = ri[t * 16];
        for (int j = 1; j < 16; j++) {
            float v = rv[t * 16 + j];
            int ii = ri[t * 16 + j];
            if (v > bv || (v == bv && ii < bi)) { bv = v; bi = ii; }
        }
        idxOut[r0 + t] = bi;
    }
}

// gather Q[idx] -> out, fused loss reduction + usage histogram
__global__ __launch_bounds__(256) void gather_out_kernel(const float* __restrict__ flat,
                                                         const float* __restrict__ Q,
                                                         const int* __restrict__ idx,
                                                         float* __restrict__ out) {
    const int t = threadIdx.x;
    const int lane = t & 63;
    const int gw = blockIdx.x * 4 + (t >> 6);   // 2048 waves, 32 rows each
    float lsum = 0.0f;
    for (int r = 0; r < 32; r++) {
        int row = gw * 32 + r;
        int k = idx[row];
        float4 q = *(const float4*)(Q + (size_t)k * DIN + lane * 4);
        float4 x = *(const float4*)(flat + (size_t)row * DIN + lane * 4);
        float dx = q.x - x.x, dy = q.y - x.y, dz = q.z - x.z, dw = q.w - x.w;
        lsum += dx * dx + dy * dy + dz * dz + dw * dw;
        float* ob = out + 1 + (size_t)row * DIN + lane * 4;  // +1 breaks 16B align -> scalar stores
        ob[0] = q.x; ob[1] = q.y; ob[2] = q.z; ob[3] = q.w;
        if (lane == 0) atomicAdd(out + 1 + TOK * DIN + k, 1.0f / (float)TOK);
    }
#pragma unroll
    for (int off = 32; off; off >>= 1) lsum += __shfl_down(lsum, off, 64);
    if (lane == 0) atomicAdd(out, lsum * (1.25f / (float)((size_t)TOK * DIN)));
}

extern "C" void kernel_launch(void* const* d_in, const int* in_sizes, int n_in,
                              void* d_out, int out_size, void* d_ws, size_t ws_size,
                              hipStream_t stream) {
    const float* inputs = (const float*)d_in[0];
    const float* bn1_gamma = (const float*)d_in[1];
    const float* bn1_beta  = (const float*)d_in[2];
    const float* W1 = (const float*)d_in[3];
    const float* b1 = (const float*)d_in[4];
    const float* E  = (const float*)d_in[5];
    const float* bn2_gamma = (const float*)d_in[6];
    const float* bn2_beta  = (const float*)d_in[7];
    const float* W2 = (const float*)d_in[8];
    const float* b2 = (const float*)d_in[9];

    float* ws = (float*)d_ws;
    float* Mp  = ws + OFF_MP;
    float* cp  = ws + OFF_CP;
    float* Q   = ws + OFF_Q;
    float* W2T = ws + OFF_W2T;
    float* u   = ws + OFF_U;
    float* cQ  = ws + OFF_CQ;
    int* idx   = (int*)(ws + OFF_IDX);
    float* out = (float*)d_out;

    hipLaunchKernelGGL(zero_out_kernel, dim3(8), dim3(256), 0, stream, out);
    hipLaunchKernelGGL(prep1_kernel, dim3(768), dim3(256), 0, stream,
                       W1, W2, bn1_beta, bn2_gamma, bn2_beta, b2, W2T, u, cQ);
    hipLaunchKernelGGL(prep2_kernel, dim3(512), dim3(256), 0, stream,
                       E, W1, W2T, bn1_gamma, cQ, Mp, Q);
    hipLaunchKernelGGL(prep3_kernel, dim3(8), dim3(256), 0, stream, E, b1, u, cp);
    hipLaunchKernelGGL(score_argmax_kernel, dim3(512), dim3(256), 0, stream, inputs, Mp, cp, idx);
    hipLaunchKernelGGL(gather_out_kernel, dim3(512), dim3(256), 0, stream, inputs, Q, idx, out);
}

// Round 2
// 564.228 us; speedup vs baseline: 1.8315x; 1.8315x over previous
//
#include <hip/hip_runtime.h>
#include <math.h>
#include <stdint.h>

#define TOK 65536
#define DIN 256
#define EDIM 512
#define KCB 2048
#define K3 768          // concatenated K: [hi|hi|lo] x [hi|lo|hi]

// workspace layout (float offsets)
#define OFF_MP   0u                         // M' fp32 [2048*256] (fallback path)
#define OFF_CP   (OFF_MP + KCB*DIN)         // c' [2048]
#define OFF_Q    (OFF_CP + KCB)             // Q  [2048*256]
#define OFF_W2T  (OFF_Q + KCB*DIN)          // W2T [512*256]
#define OFF_U    (OFF_W2T + EDIM*DIN)       // u [512]
#define OFF_CQ   (OFF_U + EDIM)             // cQ [256]
#define OFF_IDX  (OFF_CQ + DIN)             // idx [65536] ints
#define OFF_BCAT (OFF_IDX + TOK)            // Bcat bf16 [2048*768] = 786432 floats
#define OFF_PV   (OFF_BCAT + (KCB*K3)/2)    // partial vals [65536*16]
#define OFF_PI   (OFF_PV + TOK*16)          // partial idx  [65536*16]
#define OFF_AHI  (OFF_PI + TOK*16)          // Ahi bf16 [65536*256] = 8388608 floats
#define OFF_ALO  (OFF_AHI + (TOK*DIN)/2)    // Alo bf16
#define TOT_F    (OFF_ALO + (TOK*DIN)/2)

typedef short short8 __attribute__((ext_vector_type(8)));
typedef float f32x4 __attribute__((ext_vector_type(4)));

__device__ __forceinline__ unsigned short bf16rne(float x) {
    uint32_t u = __float_as_uint(x);
    u += 0x7fffu + ((u >> 16) & 1u);
    return (unsigned short)(u >> 16);
}
__device__ __forceinline__ float bfup(unsigned short h) {
    return __uint_as_float(((uint32_t)h) << 16);
}

__device__ __forceinline__ void async_load16(const void* g, void* l) {
    __builtin_amdgcn_global_load_lds((const __attribute__((address_space(1))) void*)g,
                                     (__attribute__((address_space(3))) void*)l, 16, 0, 0);
}

// zero loss scalar + usage region of d_out (harness poisons with 0xAA)
__global__ void zero_out_kernel(float* __restrict__ out) {
    int i = blockIdx.x * 256 + threadIdx.x;
    if (i == 0) out[0] = 0.0f;
    if (i < KCB) out[1 + TOK * DIN + i] = 0.0f;
}

// blocks 0..511: e=blockIdx -> W2T[e][o] and u[e];  blocks 512..767: o -> cQ[o]
__global__ void prep1_kernel(const float* __restrict__ W1, const float* __restrict__ W2,
                             const float* __restrict__ bn1_beta, const float* __restrict__ bn2_gamma,
                             const float* __restrict__ bn2_beta, const float* __restrict__ b2,
                             float* __restrict__ W2T, float* __restrict__ u, float* __restrict__ cQ) {
    __shared__ float red[256];
    const int b = blockIdx.x, t = threadIdx.x;
    const float s = 1.0f / sqrtf(1.0f + 1e-5f);
    if (b < EDIM) {
        int e = b;
        W2T[e * DIN + t] = bn2_gamma[e] * s * W2[t * EDIM + e];
        float v = bn1_beta[t] * W1[e * DIN + t];
        red[t] = v; __syncthreads();
        for (int off = 128; off; off >>= 1) { if (t < off) red[t] += red[t + off]; __syncthreads(); }
        if (t == 0) u[e] = red[0];
    } else {
        int o = b - EDIM;
        float v = bn2_beta[t] * W2[o * EDIM + t] + bn2_beta[t + 256] * W2[o * EDIM + t + 256];
        red[t] = v; __syncthreads();
        for (int off = 128; off; off >>= 1) { if (t < off) red[t] += red[t + off]; __syncthreads(); }
        if (t == 0) cQ[o] = b2[o] + red[0];
    }
}

// per block: 4 codebook rows. Writes fp32 Mp (fallback), Bcat bf16 [hi|lo|hi], fp32 Q.
__global__ __launch_bounds__(256) void prep2_kernel(const float* __restrict__ E, const float* __restrict__ W1,
                                                    const float* __restrict__ W2T, const float* __restrict__ bn1_gamma,
                                                    const float* __restrict__ cQ,
                                                    float* __restrict__ Mp, float* __restrict__ Q,
                                                    unsigned short* __restrict__ Bcat) {
    __shared__ float Elds[EDIM * 4];
    const int k0 = blockIdx.x * 4, t = threadIdx.x;
    const float4* src = (const float4*)(E + (size_t)k0 * EDIM);
    for (int i = t; i < 512; i += 256) {
        float4 v = src[i];
        int kk = i >> 7;
        int e = (i & 127) << 2;
        Elds[(e + 0) * 4 + kk] = v.x; Elds[(e + 1) * 4 + kk] = v.y;
        Elds[(e + 2) * 4 + kk] = v.z; Elds[(e + 3) * 4 + kk] = v.w;
    }
    __syncthreads();
    float m0 = 0, m1 = 0, m2 = 0, m3 = 0, q0 = 0, q1 = 0, q2 = 0, q3 = 0;
    for (int e = 0; e < EDIM; e++) {
        float4 ev = *(const float4*)&Elds[e * 4];
        float w1 = W1[e * DIN + t];
        float w2 = W2T[e * DIN + t];
        m0 += ev.x * w1; m1 += ev.y * w1; m2 += ev.z * w1; m3 += ev.w * w1;
        q0 += ev.x * w2; q1 += ev.y * w2; q2 += ev.z * w2; q3 += ev.w * w2;
    }
    const float s = 1.0f / sqrtf(1.0f + 1e-5f);
    const float gs = bn1_gamma[t] * s;
    const float cq = cQ[t];
    float mv[4] = {gs * m0, gs * m1, gs * m2, gs * m3};
    float qv[4] = {q0 + cq, q1 + cq, q2 + cq, q3 + cq};
#pragma unroll
    for (int i = 0; i < 4; i++) {
        Mp[(size_t)(k0 + i) * DIN + t] = mv[i];
        Q[(size_t)(k0 + i) * DIN + t] = qv[i];
        unsigned short h = bf16rne(mv[i]);
        unsigned short l = bf16rne(mv[i] - bfup(h));
        size_t rb = (size_t)(k0 + i) * K3;
        Bcat[rb + t] = h;            // hi block (k 0..255)
        Bcat[rb + 256 + t] = l;      // lo block (k 256..511)
        Bcat[rb + 512 + t] = h;      // hi again (k 512..767)
    }
}

// c'[k] = sum_e E[k][e]*(b1[e]+u[e]) - 0.5*sum_e E[k][e]^2
__global__ void prep3_kernel(const float* __restrict__ E, const float* __restrict__ b1,
                             const float* __restrict__ u, float* __restrict__ cp) {
    int k = blockIdx.x * 256 + threadIdx.x;
    const float4* er = (const float4*)(E + (size_t)k * EDIM);
    float sa = 0.0f, sb = 0.0f;
    for (int i = 0; i < 128; i++) {
        float4 ev = er[i];
        int e = i * 4;
        sa += ev.x * (b1[e] + u[e]) + ev.y * (b1[e + 1] + u[e + 1])
            + ev.z * (b1[e + 2] + u[e + 2]) + ev.w * (b1[e + 3] + u[e + 3]);
        sb += ev.x * ev.x + ev.y * ev.y + ev.z * ev.z + ev.w * ev.w;
    }
    cp[k] = sa - 0.5f * sb;
}

// flat fp32 -> Ahi/Alo bf16 (RNE split)
__global__ __launch_bounds__(256) void convertA_kernel(const float* __restrict__ flat,
                                                       uint4* __restrict__ Ahi, uint4* __restrict__ Alo) {
    int gid = blockIdx.x * 256 + threadIdx.x;
    const float4* s = (const float4*)flat;
    float4 v0 = s[(size_t)gid * 2], v1 = s[(size_t)gid * 2 + 1];
    float f[8] = {v0.x, v0.y, v0.z, v0.w, v1.x, v1.y, v1.z, v1.w};
    uint32_t h[8], l[8];
#pragma unroll
    for (int i = 0; i < 8; i++) {
        unsigned short hh = bf16rne(f[i]);
        h[i] = hh;
        l[i] = bf16rne(f[i] - bfup(hh));
    }
    uint4 H, L;
    H.x = h[0] | (h[1] << 16); H.y = h[2] | (h[3] << 16);
    H.z = h[4] | (h[5] << 16); H.w = h[6] | (h[7] << 16);
    L.x = l[0] | (l[1] << 16); L.y = l[2] | (l[3] << 16);
    L.z = l[4] | (l[5] << 16); L.w = l[6] | (l[7] << 16);
    Ahi[gid] = H; Alo[gid] = L;
}

// MFMA scorer: C[128m x 128n] over K=768 (split-bf16 triple product), fused argmax
// over the block's 128 codes -> partial (val, idx) per (row, n-block).
__global__ __launch_bounds__(256) void score_mfma_kernel(const unsigned short* __restrict__ Ahi,
                                                         const unsigned short* __restrict__ Alo,
                                                         const unsigned short* __restrict__ Bcat,
                                                         const float* __restrict__ cp,
                                                         float* __restrict__ pval, int* __restrict__ pidx) {
    __shared__ __align__(16) unsigned short As[128 * 32];  // [row][k] 8 KB
    __shared__ __align__(16) unsigned short Bs[128 * 32];  // [code][k] 8 KB
    __shared__ float ev[2 * 128];
    __shared__ int   ei[2 * 128];
    const int t = threadIdx.x;
    const int lane = t & 63;
    const int w = t >> 6;            // wave 0..3
    const int wm = w & 1, wn = w >> 1;
    const int m0 = blockIdx.x * 128;
    const int n0 = blockIdx.y * 128;

    // staging: load unit = 16 rows (64 lanes x 16B). wave w stages units 2w,2w+1 of A and B.
    const int srow = lane >> 2;      // 0..15
    const int sq = lane & 3;         // 16B quarter of a 64B row-chunk
    const int au0 = 2 * w, au1 = 2 * w + 1;
    const size_t aOff0 = (size_t)(m0 + 16 * au0 + srow) * DIN + sq * 8;
    const size_t aOff1 = (size_t)(m0 + 16 * au1 + srow) * DIN + sq * 8;
    const size_t bOff0 = (size_t)(n0 + 16 * au0 + srow) * K3 + sq * 8;
    const size_t bOff1 = (size_t)(n0 + 16 * au1 + srow) * K3 + sq * 8;

    f32x4 acc[4][4];
#pragma unroll
    for (int i = 0; i < 4; i++)
#pragma unroll
        for (int j = 0; j < 4; j++) acc[i][j] = (f32x4){0.f, 0.f, 0.f, 0.f};

    const int fk = (lane >> 4) * 8;       // fragment k sub-offset
    const int fr = lane & 15;             // fragment row/col index

    for (int kc = 0; kc < 24; kc++) {
        const unsigned short* Asrc = (kc < 16 ? Ahi : Alo);
        const int akoff = (kc & 7) * 32;  // kc 0-7: hi k-chunks; 8-15: hi again; 16-23: lo
        const int bkoff = kc * 32;
        __syncthreads();
        async_load16(Asrc + aOff0 + akoff, &As[au0 * 512]);
        async_load16(Asrc + aOff1 + akoff, &As[au1 * 512]);
        async_load16(Bcat + bOff0 + bkoff, &Bs[au0 * 512]);
        async_load16(Bcat + bOff1 + bkoff, &Bs[au1 * 512]);
        __syncthreads();
        short8 af[4], bf[4];
#pragma unroll
        for (int mt = 0; mt < 4; mt++)
            af[mt] = *(const short8*)&As[(wm * 64 + mt * 16 + fr) * 32 + fk];
#pragma unroll
        for (int nt = 0; nt < 4; nt++)
            bf[nt] = *(const short8*)&Bs[(wn * 64 + nt * 16 + fr) * 32 + fk];
#pragma unroll
        for (int mt = 0; mt < 4; mt++)
#pragma unroll
            for (int nt = 0; nt < 4; nt++)
                acc[mt][nt] = __builtin_amdgcn_mfma_f32_16x16x32_bf16(af[mt], bf[nt], acc[mt][nt], 0, 0, 0);
    }

    // epilogue: add c', argmax over this block's 128 codes per row
    const int colb = n0 + wn * 64 + fr;
    float cpv[4];
#pragma unroll
    for (int nt = 0; nt < 4; nt++) cpv[nt] = cp[colb + nt * 16];
#pragma unroll
    for (int mt = 0; mt < 4; mt++) {
#pragma unroll
        for (int r = 0; r < 4; r++) {
            float bv = acc[mt][0][r] + cpv[0];
            int bc = colb;
#pragma unroll
            for (int nt = 1; nt < 4; nt++) {
                float v = acc[mt][nt][r] + cpv[nt];
                if (v > bv) { bv = v; bc = colb + nt * 16; }  // ties -> lower col (ascending)
            }
#pragma unroll
            for (int xm = 1; xm < 16; xm <<= 1) {
                float ov = __shfl_xor(bv, xm, 64);
                int oc = __shfl_xor(bc, xm, 64);
                if (ov > bv || (ov == bv && oc < bc)) { bv = ov; bc = oc; }
            }
            if (fr == 0) {
                int row = wm * 64 + mt * 16 + ((lane >> 4) << 2) + r;
                ev[wn * 128 + row] = bv;
                ei[wn * 128 + row] = bc;
            }
        }
    }
    __syncthreads();
    if (t < 128) {
        float v0 = ev[t]; int c0 = ei[t];
        float v1 = ev[128 + t]; int c1 = ei[128 + t];
        if (v1 > v0) { v0 = v1; c0 = c1; }   // wn=1 cols always higher -> strict >
        pval[(size_t)(m0 + t) * 16 + blockIdx.y] = v0;
        pidx[(size_t)(m0 + t) * 16 + blockIdx.y] = c0;
    }
}

__global__ __launch_bounds__(256) void reduce_idx_kernel(const float* __restrict__ pval,
                                                         const int* __restrict__ pidx,
                                                         int* __restrict__ idxOut) {
    int m = blockIdx.x * 256 + threadIdx.x;
    const float* pv = pval + (size_t)m * 16;
    const int* pi = pidx + (size_t)m * 16;
    float bv = pv[0]; int bc = pi[0];
#pragma unroll
    for (int j = 1; j < 16; j++) {
        float v = pv[j]; int c = pi[j];
        if (v > bv || (v == bv && c < bc)) { bv = v; bc = c; }
    }
    idxOut[m] = bc;
}

// fallback fp32 scorer (round-1, used when ws too small for bf16 path)
__global__ __launch_bounds__(256) void score_argmax_kernel(const float* __restrict__ flat,
                                                           const float* __restrict__ Mp,
                                                           const float* __restrict__ cp,
                                                           int* __restrict__ idxOut) {
    __shared__ float As[8 * 128];
    __shared__ float Bs[8 * 128];
    __shared__ float rv[128 * 16];
    __shared__ int   ri[128 * 16];
    const int t = threadIdx.x;
    const int ty = t >> 4, tx = t & 15;
    const int r0 = blockIdx.x * 128;
    const int sm = t >> 1;
    const int sk = (t & 1) * 4;

    float bestv[8];
    int besti[8];
#pragma unroll
    for (int i = 0; i < 8; i++) { bestv[i] = -3.4e38f; besti[i] = 0; }

    const float* Ab = flat + (size_t)(r0 + sm) * DIN + sk;

    for (int ch = 0; ch < 16; ch++) {
        float acc[8][8];
#pragma unroll
        for (int i = 0; i < 8; i++)
#pragma unroll
            for (int j = 0; j < 8; j++) acc[i][j] = 0.0f;

        const float* Bb = Mp + (size_t)(ch * 128 + sm) * DIN + sk;
        float4 av = *(const float4*)(Ab);
        float4 bv = *(const float4*)(Bb);

        for (int ks = 0; ks < 32; ks++) {
            __syncthreads();
            As[(sk + 0) * 128 + sm] = av.x; As[(sk + 1) * 128 + sm] = av.y;
            As[(sk + 2) * 128 + sm] = av.z; As[(sk + 3) * 128 + sm] = av.w;
            Bs[(sk + 0) * 128 + sm] = bv.x; Bs[(sk + 1) * 128 + sm] = bv.y;
            Bs[(sk + 2) * 128 + sm] = bv.z; Bs[(sk + 3) * 128 + sm] = bv.w;
            __syncthreads();
            if (ks < 31) {
                av = *(const float4*)(Ab + (ks + 1) * 8);
                bv = *(const float4*)(Bb + (ks + 1) * 8);
            }
#pragma unroll
            for (int k = 0; k < 8; k++) {
                float4 a0 = *(const float4*)&As[k * 128 + ty * 8];
                float4 a1 = *(const float4*)&As[k * 128 + ty * 8 + 4];
                float4 b0 = *(const float4*)&Bs[k * 128 + tx * 8];
                float4 b1 = *(const float4*)&Bs[k * 128 + tx * 8 + 4];
                float a[8] = {a0.x, a0.y, a0.z, a0.w, a1.x, a1.y, a1.z, a1.w};
                float b[8] = {b0.x, b0.y, b0.z, b0.w, b1.x, b1.y, b1.z, b1.w};
#pragma unroll
                for (int i = 0; i < 8; i++)
#pragma unroll
                    for (int j = 0; j < 8; j++) acc[i][j] += a[i] * b[j];
            }
        }
#pragma unroll
        for (int j = 0; j < 8; j++) {
            int code = ch * 128 + tx * 8 + j;
            float cj = cp[code];
#pragma unroll
            for (int i = 0; i < 8; i++) {
                float v = acc[i][j] + cj;
                if (v > bestv[i]) { bestv[i] = v; besti[i] = code; }
            }
        }
    }
#pragma unroll
    for (int i = 0; i < 8; i++) {
        rv[(ty * 8 + i) * 16 + tx] = bestv[i];
        ri[(ty * 8 + i) * 16 + tx] = besti[i];
    }
    __syncthreads();
    if (t < 128) {
        float bv = rv[t * 16];
        int bi = ri[t * 16];
        for (int j = 1; j < 16; j++) {
            float v = rv[t * 16 + j];
            int ii = ri[t * 16 + j];
            if (v > bv || (v == bv && ii < bi)) { bv = v; bi = ii; }
        }
        idxOut[r0 + t] = bi;
    }
}

// gather Q[idx] -> out, fused loss reduction + usage histogram
__global__ __launch_bounds__(256) void gather_out_kernel(const float* __restrict__ flat,
                                                         const float* __restrict__ Q,
                                                         const int* __restrict__ idx,
                                                         float* __restrict__ out) {
    const int t = threadIdx.x;
    const int lane = t & 63;
    const int gw = blockIdx.x * 4 + (t >> 6);
    float lsum = 0.0f;
    for (int r = 0; r < 32; r++) {
        int row = gw * 32 + r;
        int k = idx[row];
        float4 q = *(const float4*)(Q + (size_t)k * DIN + lane * 4);
        float4 x = *(const float4*)(flat + (size_t)row * DIN + lane * 4);
        float dx = q.x - x.x, dy = q.y - x.y, dz = q.z - x.z, dw = q.w - x.w;
        lsum += dx * dx + dy * dy + dz * dz + dw * dw;
        float* ob = out + 1 + (size_t)row * DIN + lane * 4;
        ob[0] = q.x; ob[1] = q.y; ob[2] = q.z; ob[3] = q.w;
        if (lane == 0) atomicAdd(out + 1 + TOK * DIN + k, 1.0f / (float)TOK);
    }
#pragma unroll
    for (int off = 32; off; off >>= 1) lsum += __shfl_down(lsum, off, 64);
    if (lane == 0) atomicAdd(out, lsum * (1.25f / (float)((size_t)TOK * DIN)));
}

extern "C" void kernel_launch(void* const* d_in, const int* in_sizes, int n_in,
                              void* d_out, int out_size, void* d_ws, size_t ws_size,
                              hipStream_t stream) {
    const float* inputs = (const float*)d_in[0];
    const float* bn1_gamma = (const float*)d_in[1];
    const float* bn1_beta  = (const float*)d_in[2];
    const float* W1 = (const float*)d_in[3];
    const float* b1 = (const float*)d_in[4];
    const float* E  = (const float*)d_in[5];
    const float* bn2_gamma = (const float*)d_in[6];
    const float* bn2_beta  = (const float*)d_in[7];
    const float* W2 = (const float*)d_in[8];
    const float* b2 = (const float*)d_in[9];

    float* ws = (float*)d_ws;
    float* Mp  = ws + OFF_MP;
    float* cp  = ws + OFF_CP;
    float* Q   = ws + OFF_Q;
    float* W2T = ws + OFF_W2T;
    float* u   = ws + OFF_U;
    float* cQ  = ws + OFF_CQ;
    int* idx   = (int*)(ws + OFF_IDX);
    unsigned short* Bcat = (unsigned short*)(ws + OFF_BCAT);
    float* pval = ws + OFF_PV;
    int* pidx   = (int*)(ws + OFF_PI);
    unsigned short* AhiP = (unsigned short*)(ws + OFF_AHI);
    unsigned short* AloP = (unsigned short*)(ws + OFF_ALO);
    float* out = (float*)d_out;

    const bool fast = ws_size >= (size_t)TOT_F * 4;

    hipLaunchKernelGGL(zero_out_kernel, dim3(8), dim3(256), 0, stream, out);
    hipLaunchKernelGGL(prep1_kernel, dim3(768), dim3(256), 0, stream,
                       W1, W2, bn1_beta, bn2_gamma, bn2_beta, b2, W2T, u, cQ);
    hipLaunchKernelGGL(prep2_kernel, dim3(512), dim3(256), 0, stream,
                       E, W1, W2T, bn1_gamma, cQ, Mp, Q, Bcat);
    hipLaunchKernelGGL(prep3_kernel, dim3(8), dim3(256), 0, stream, E, b1, u, cp);
    if (fast) {
        hipLaunchKernelGGL(convertA_kernel, dim3(8192), dim3(256), 0, stream,
                           inputs, (uint4*)AhiP, (uint4*)AloP);
        hipLaunchKernelGGL(score_mfma_kernel, dim3(512, 16), dim3(256), 0, stream,
                           AhiP, AloP, Bcat, cp, pval, pidx);
        hipLaunchKernelGGL(reduce_idx_kernel, dim3(256), dim3(256), 0, stream, pval, pidx, idx);
    } else {
        hipLaunchKernelGGL(score_argmax_kernel, dim3(512), dim3(256), 0, stream, inputs, Mp, cp, idx);
    }
    hipLaunchKernelGGL(gather_out_kernel, dim3(512), dim3(256), 0, stream, inputs, Q, idx, out);
}

// Round 3
// 478.157 us; speedup vs baseline: 2.1612x; 1.1800x over previous
//
#include <hip/hip_runtime.h>
#include <math.h>
#include <stdint.h>

#define TOK 65536
#define DIN 256
#define EDIM 512
#define KCB 2048
#define NTA 4096        // A m-tiles (65536/16)
#define NTB 128         // B n-tiles (2048/16)

// workspace layout (float offsets), all 64-float aligned
#define OFF_MP   0u                     // M' fp32 [2048*256]
#define OFF_CP   524288u                // c' [2048]
#define OFF_Q    526336u                // Q [2048*256]
#define OFF_W2T  1050624u               // W2T [512*256]
#define OFF_U    1181696u               // u [512]
#define OFF_CQ   1182208u               // cQ [256]
#define OFF_IDX  1182464u               // idx [65536] ints
#define OFF_PV   1248000u               // partial vals [65536*16]
#define OFF_PI   2296576u               // partial idx [65536*16]
#define OFF_AH   3345152u               // Ahi packed bf16 [8][4096][512]
#define OFF_AL   11733760u              // Alo packed
#define OFF_BH   20122368u              // Bhi packed bf16 [8][128][512]
#define OFF_BL   20384512u              // Blo packed
#define TOT_F    20646656u

typedef short short8 __attribute__((ext_vector_type(8)));
typedef float f32x4 __attribute__((ext_vector_type(4)));

__device__ __forceinline__ unsigned short bf16rne(float x) {
    uint32_t u = __float_as_uint(x);
    u += 0x7fffu + ((u >> 16) & 1u);
    return (unsigned short)(u >> 16);
}
__device__ __forceinline__ float bfup(unsigned short h) {
    return __uint_as_float(((uint32_t)h) << 16);
}
__device__ __forceinline__ void async_load16(const void* g, void* l) {
    __builtin_amdgcn_global_load_lds((const __attribute__((address_space(1))) void*)g,
                                     (__attribute__((address_space(3))) void*)l, 16, 0, 0);
}

__global__ void zero_out_kernel(float* __restrict__ out) {
    int i = blockIdx.x * 256 + threadIdx.x;
    if (i == 0) out[0] = 0.0f;
    if (i < KCB) out[1 + TOK * DIN + i] = 0.0f;
}

// blocks 0..511: e -> W2T[e][o], u[e];  512..767: o -> cQ[o]
__global__ void prep1_kernel(const float* __restrict__ W1, const float* __restrict__ W2,
                             const float* __restrict__ bn1_beta, const float* __restrict__ bn2_gamma,
                             const float* __restrict__ bn2_beta, const float* __restrict__ b2,
                             float* __restrict__ W2T, float* __restrict__ u, float* __restrict__ cQ) {
    __shared__ float red[256];
    const int b = blockIdx.x, t = threadIdx.x;
    const float s = 1.0f / sqrtf(1.0f + 1e-5f);
    if (b < EDIM) {
        int e = b;
        W2T[e * DIN + t] = bn2_gamma[e] * s * W2[t * EDIM + e];
        float v = bn1_beta[t] * W1[e * DIN + t];
        red[t] = v; __syncthreads();
        for (int off = 128; off; off >>= 1) { if (t < off) red[t] += red[t + off]; __syncthreads(); }
        if (t == 0) u[e] = red[0];
    } else {
        int o = b - EDIM;
        float v = bn2_beta[t] * W2[o * EDIM + t] + bn2_beta[t + 256] * W2[o * EDIM + t + 256];
        red[t] = v; __syncthreads();
        for (int off = 128; off; off >>= 1) { if (t < off) red[t] += red[t + off]; __syncthreads(); }
        if (t == 0) cQ[o] = b2[o] + red[0];
    }
}

// per block: 4 codebook rows -> Mp fp32, Q fp32
__global__ __launch_bounds__(256) void prep2_kernel(const float* __restrict__ E, const float* __restrict__ W1,
                                                    const float* __restrict__ W2T, const float* __restrict__ bn1_gamma,
                                                    const float* __restrict__ cQ,
                                                    float* __restrict__ Mp, float* __restrict__ Q) {
    __shared__ float Elds[EDIM * 4];
    const int k0 = blockIdx.x * 4, t = threadIdx.x;
    const float4* src = (const float4*)(E + (size_t)k0 * EDIM);
    for (int i = t; i < 512; i += 256) {
        float4 v = src[i];
        int kk = i >> 7;
        int e = (i & 127) << 2;
        Elds[(e + 0) * 4 + kk] = v.x; Elds[(e + 1) * 4 + kk] = v.y;
        Elds[(e + 2) * 4 + kk] = v.z; Elds[(e + 3) * 4 + kk] = v.w;
    }
    __syncthreads();
    float m0 = 0, m1 = 0, m2 = 0, m3 = 0, q0 = 0, q1 = 0, q2 = 0, q3 = 0;
    for (int e = 0; e < EDIM; e++) {
        float4 ev = *(const float4*)&Elds[e * 4];
        float w1 = W1[e * DIN + t];
        float w2 = W2T[e * DIN + t];
        m0 += ev.x * w1; m1 += ev.y * w1; m2 += ev.z * w1; m3 += ev.w * w1;
        q0 += ev.x * w2; q1 += ev.y * w2; q2 += ev.z * w2; q3 += ev.w * w2;
    }
    const float s = 1.0f / sqrtf(1.0f + 1e-5f);
    const float gs = bn1_gamma[t] * s;
    const float cq = cQ[t];
    float mv[4] = {gs * m0, gs * m1, gs * m2, gs * m3};
    float qv[4] = {q0 + cq, q1 + cq, q2 + cq, q3 + cq};
#pragma unroll
    for (int i = 0; i < 4; i++) {
        Mp[(size_t)(k0 + i) * DIN + t] = mv[i];
        Q[(size_t)(k0 + i) * DIN + t] = qv[i];
    }
}

// c'[k] = sum_e E[k][e]*(b1[e]+u[e]) - 0.5*sum_e E[k][e]^2
__global__ void prep3_kernel(const float* __restrict__ E, const float* __restrict__ b1,
                             const float* __restrict__ u, float* __restrict__ cp) {
    int k = blockIdx.x * 256 + threadIdx.x;
    const float4* er = (const float4*)(E + (size_t)k * EDIM);
    float sa = 0.0f, sb = 0.0f;
    for (int i = 0; i < 128; i++) {
        float4 ev = er[i];
        int e = i * 4;
        sa += ev.x * (b1[e] + u[e]) + ev.y * (b1[e + 1] + u[e + 1])
            + ev.z * (b1[e + 2] + u[e + 2]) + ev.w * (b1[e + 3] + u[e + 3]);
        sb += ev.x * ev.x + ev.y * ev.y + ev.z * ev.z + ev.w * ev.w;
    }
    cp[k] = sa - 0.5f * sb;
}

// X[R x 256] fp32 -> hi/lo bf16 in MFMA fragment-tile order:
// plane kc (0..7), tile tt (16 rows), 1KB block: lane L owns
// X[tt*16 + (L&15)][kc*32 + (L>>4)*8 + 0..7]. Block = 32 rows (2 tiles).
__global__ __launch_bounds__(256) void pack_kernel(const float* __restrict__ X,
                                                   unsigned short* __restrict__ Hp,
                                                   unsigned short* __restrict__ Lp, int ntiles) {
    __shared__ __align__(16) unsigned short Hs[32 * 264];  // pitch 264 halves = 528 B (16B-aligned, bank-safe)
    __shared__ __align__(16) unsigned short Ls[32 * 264];
    const int t = threadIdx.x;
    const int r0 = blockIdx.x * 32;
    const float4* src = (const float4*)(X + (size_t)r0 * DIN);
#pragma unroll
    for (int i = 0; i < 8; i++) {
        int id = i * 256 + t;
        int row = id >> 6, c4 = id & 63;
        float4 v = src[id];
        float f[4] = {v.x, v.y, v.z, v.w};
        ushort4 H, L;
        unsigned short* hp = (unsigned short*)&H;
        unsigned short* lp = (unsigned short*)&L;
#pragma unroll
        for (int j = 0; j < 4; j++) {
            unsigned short h = bf16rne(f[j]);
            hp[j] = h;
            lp[j] = bf16rne(f[j] - bfup(h));
        }
        *(ushort4*)&Hs[row * 264 + c4 * 4] = H;
        *(ushort4*)&Ls[row * 264 + c4 * 4] = L;
    }
    __syncthreads();
    const int lane = t & 63, w = t >> 6;
#pragma unroll
    for (int q = 0; q < 4; q++) {
        int fb = q * 4 + w;              // 0..15
        int tl = fb >> 3, kc = fb & 7;
        int srow = tl * 16 + (lane & 15);
        int scol = kc * 32 + (lane >> 4) * 8;
        short8 vh = *(const short8*)&Hs[srow * 264 + scol];
        short8 vl = *(const short8*)&Ls[srow * 264 + scol];
        size_t off = ((size_t)kc * ntiles + (r0 >> 4) + tl) * 512 + lane * 8;
        *(short8*)&Hp[off] = vh;
        *(short8*)&Lp[off] = vl;
    }
}

// MFMA scorer. C[128m x 128n], K=256 split-bf16 (ahi*bhi + ahi*blo + alo*bhi),
// 8 k-chunks of 32, 48 MFMA per barrier interval, conflict-free LDS by construction.
// grid (16 n-blocks fastest, 512 m-blocks) -> packed B (2MB) stays L2-resident.
__global__ __launch_bounds__(256, 3) void score_mfma_kernel(const unsigned short* __restrict__ Ah,
                                                            const unsigned short* __restrict__ Al,
                                                            const unsigned short* __restrict__ Bh,
                                                            const unsigned short* __restrict__ Bl,
                                                            const float* __restrict__ cp,
                                                            float* __restrict__ pval, int* __restrict__ pidx) {
    __shared__ __align__(16) unsigned short S[4 * 8 * 512];  // 32 KB: [arr 0..3][tile 0..7][512 halves]
    __shared__ float ev[2 * 128];
    __shared__ int   ei[2 * 128];
    const int t = threadIdx.x, lane = t & 63, w = t >> 6;
    const int wm = w & 1, wn = w >> 1;
    const int nb = blockIdx.x;
    const int m0 = blockIdx.y * 128;
    const int n0 = nb * 128;
    const int mt0 = m0 >> 4, nt0 = n0 >> 4;

    const unsigned short* gsrc = (w == 0) ? Ah : (w == 1) ? Al : (w == 2) ? Bh : Bl;
    const int gtile0 = (w < 2) ? mt0 : nt0;
    const int gnt = (w < 2) ? NTA : NTB;
    unsigned short* ldst = &S[w * 4096];

    f32x4 acc[4][4];
#pragma unroll
    for (int i = 0; i < 4; i++)
#pragma unroll
        for (int j = 0; j < 4; j++) acc[i][j] = (f32x4){0.f, 0.f, 0.f, 0.f};

    for (int kc = 0; kc < 8; kc++) {
        __syncthreads();
        const unsigned short* gs = gsrc + ((size_t)kc * gnt + gtile0) * 512 + lane * 8;
#pragma unroll
        for (int u = 0; u < 8; u++)
            async_load16(gs + u * 512, ldst + u * 512);
        __syncthreads();

        short8 afh[4], afl[4];
#pragma unroll
        for (int mt = 0; mt < 4; mt++) {
            afh[mt] = *(const short8*)&S[0 * 4096 + (wm * 4 + mt) * 512 + lane * 8];
            afl[mt] = *(const short8*)&S[1 * 4096 + (wm * 4 + mt) * 512 + lane * 8];
        }
#pragma unroll
        for (int nt = 0; nt < 4; nt++) {
            short8 bfh = *(const short8*)&S[2 * 4096 + (wn * 4 + nt) * 512 + lane * 8];
            short8 bfl = *(const short8*)&S[3 * 4096 + (wn * 4 + nt) * 512 + lane * 8];
#pragma unroll
            for (int mt = 0; mt < 4; mt++) {
                acc[mt][nt] = __builtin_amdgcn_mfma_f32_16x16x32_bf16(afl[mt], bfh, acc[mt][nt], 0, 0, 0);
                acc[mt][nt] = __builtin_amdgcn_mfma_f32_16x16x32_bf16(afh[mt], bfl, acc[mt][nt], 0, 0, 0);
                acc[mt][nt] = __builtin_amdgcn_mfma_f32_16x16x32_bf16(afh[mt], bfh, acc[mt][nt], 0, 0, 0);
            }
        }
    }

    // epilogue: add c', argmax over this block's 128 codes per row
    const int fr = lane & 15;
    const int colb = n0 + wn * 64 + fr;
    float cpv[4];
#pragma unroll
    for (int nt = 0; nt < 4; nt++) cpv[nt] = cp[colb + nt * 16];
#pragma unroll
    for (int mt = 0; mt < 4; mt++) {
#pragma unroll
        for (int r = 0; r < 4; r++) {
            float bv = acc[mt][0][r] + cpv[0];
            int bc = colb;
#pragma unroll
            for (int nt = 1; nt < 4; nt++) {
                float v = acc[mt][nt][r] + cpv[nt];
                if (v > bv) { bv = v; bc = colb + nt * 16; }
            }
#pragma unroll
            for (int xm = 1; xm < 16; xm <<= 1) {
                float ov = __shfl_xor(bv, xm, 64);
                int oc = __shfl_xor(bc, xm, 64);
                if (ov > bv || (ov == bv && oc < bc)) { bv = ov; bc = oc; }
            }
            if (fr == 0) {
                int row = wm * 64 + mt * 16 + ((lane >> 4) << 2) + r;
                ev[wn * 128 + row] = bv;
                ei[wn * 128 + row] = bc;
            }
        }
    }
    __syncthreads();
    if (t < 128) {
        float v0 = ev[t]; int c0 = ei[t];
        float v1 = ev[128 + t]; int c1 = ei[128 + t];
        if (v1 > v0) { v0 = v1; c0 = c1; }   // wn=1 cols strictly higher -> strict >
        pval[(size_t)(m0 + t) * 16 + nb] = v0;
        pidx[(size_t)(m0 + t) * 16 + nb] = c0;
    }
}

__global__ __launch_bounds__(256) void reduce_idx_kernel(const float* __restrict__ pval,
                                                         const int* __restrict__ pidx,
                                                         int* __restrict__ idxOut) {
    int m = blockIdx.x * 256 + threadIdx.x;
    const float* pv = pval + (size_t)m * 16;
    const int* pi = pidx + (size_t)m * 16;
    float bv = pv[0]; int bc = pi[0];
#pragma unroll
    for (int j = 1; j < 16; j++) {
        float v = pv[j]; int c = pi[j];
        if (v > bv || (v == bv && c < bc)) { bv = v; bc = c; }
    }
    idxOut[m] = bc;
}

// fallback fp32 scorer (used only if ws too small)
__global__ __launch_bounds__(256) void score_argmax_kernel(const float* __restrict__ flat,
                                                           const float* __restrict__ Mp,
                                                           const float* __restrict__ cp,
                                                           int* __restrict__ idxOut) {
    __shared__ float As[8 * 128];
    __shared__ float Bs[8 * 128];
    __shared__ float rv[128 * 16];
    __shared__ int   ri[128 * 16];
    const int t = threadIdx.x;
    const int ty = t >> 4, tx = t & 15;
    const int r0 = blockIdx.x * 128;
    const int sm = t >> 1;
    const int sk = (t & 1) * 4;
    float bestv[8];
    int besti[8];
#pragma unroll
    for (int i = 0; i < 8; i++) { bestv[i] = -3.4e38f; besti[i] = 0; }
    const float* Ab = flat + (size_t)(r0 + sm) * DIN + sk;
    for (int ch = 0; ch < 16; ch++) {
        float acc[8][8];
#pragma unroll
        for (int i = 0; i < 8; i++)
#pragma unroll
            for (int j = 0; j < 8; j++) acc[i][j] = 0.0f;
        const float* Bb = Mp + (size_t)(ch * 128 + sm) * DIN + sk;
        float4 av = *(const float4*)(Ab);
        float4 bv = *(const float4*)(Bb);
        for (int ks = 0; ks < 32; ks++) {
            __syncthreads();
            As[(sk + 0) * 128 + sm] = av.x; As[(sk + 1) * 128 + sm] = av.y;
            As[(sk + 2) * 128 + sm] = av.z; As[(sk + 3) * 128 + sm] = av.w;
            Bs[(sk + 0) * 128 + sm] = bv.x; Bs[(sk + 1) * 128 + sm] = bv.y;
            Bs[(sk + 2) * 128 + sm] = bv.z; Bs[(sk + 3) * 128 + sm] = bv.w;
            __syncthreads();
            if (ks < 31) {
                av = *(const float4*)(Ab + (ks + 1) * 8);
                bv = *(const float4*)(Bb + (ks + 1) * 8);
            }
#pragma unroll
            for (int k = 0; k < 8; k++) {
                float4 a0 = *(const float4*)&As[k * 128 + ty * 8];
                float4 a1 = *(const float4*)&As[k * 128 + ty * 8 + 4];
                float4 b0 = *(const float4*)&Bs[k * 128 + tx * 8];
                float4 b1 = *(const float4*)&Bs[k * 128 + tx * 8 + 4];
                float a[8] = {a0.x, a0.y, a0.z, a0.w, a1.x, a1.y, a1.z, a1.w};
                float b[8] = {b0.x, b0.y, b0.z, b0.w, b1.x, b1.y, b1.z, b1.w};
#pragma unroll
                for (int i = 0; i < 8; i++)
#pragma unroll
                    for (int j = 0; j < 8; j++) acc[i][j] += a[i] * b[j];
            }
        }
#pragma unroll
        for (int j = 0; j < 8; j++) {
            int code = ch * 128 + tx * 8 + j;
            float cj = cp[code];
#pragma unroll
            for (int i = 0; i < 8; i++) {
                float v = acc[i][j] + cj;
                if (v > bestv[i]) { bestv[i] = v; besti[i] = code; }
            }
        }
    }
#pragma unroll
    for (int i = 0; i < 8; i++) {
        rv[(ty * 8 + i) * 16 + tx] = bestv[i];
        ri[(ty * 8 + i) * 16 + tx] = besti[i];
    }
    __syncthreads();
    if (t < 128) {
        float bv = rv[t * 16];
        int bi = ri[t * 16];
        for (int j = 1; j < 16; j++) {
            float v = rv[t * 16 + j];
            int ii = ri[t * 16 + j];
            if (v > bv || (v == bv && ii < bi)) { bv = v; bi = ii; }
        }
        idxOut[r0 + t] = bi;
    }
}

// gather Q[idx] -> out (+1 offset), dword-coalesced, fused loss + usage histogram
__global__ __launch_bounds__(256) void gather_out_kernel(const float* __restrict__ flat,
                                                         const float* __restrict__ Q,
                                                         const int* __restrict__ idx,
                                                         float* __restrict__ out) {
    const int t = threadIdx.x;
    const int lane = t & 63;
    const int gw = blockIdx.x * 4 + (t >> 6);
    float lsum = 0.0f;
    for (int r = 0; r < 32; r++) {
        int row = gw * 32 + r;
        int k = idx[row];
        const float* qr = Q + (size_t)k * DIN;
        const float* xr = flat + (size_t)row * DIN;
        float* ob = out + 1 + (size_t)row * DIN;
#pragma unroll
        for (int c = 0; c < 4; c++) {
            int j = lane + 64 * c;
            float q = qr[j];
            float d = q - xr[j];
            lsum += d * d;
            ob[j] = q;       // lanes write consecutive dwords -> coalesced
        }
        if (lane == 0) atomicAdd(out + 1 + TOK * DIN + k, 1.0f / (float)TOK);
    }
#pragma unroll
    for (int off = 32; off; off >>= 1) lsum += __shfl_down(lsum, off, 64);
    if (lane == 0) atomicAdd(out, lsum * (1.25f / (float)((size_t)TOK * DIN)));
}

extern "C" void kernel_launch(void* const* d_in, const int* in_sizes, int n_in,
                              void* d_out, int out_size, void* d_ws, size_t ws_size,
                              hipStream_t stream) {
    const float* inputs = (const float*)d_in[0];
    const float* bn1_gamma = (const float*)d_in[1];
    const float* bn1_beta  = (const float*)d_in[2];
    const float* W1 = (const float*)d_in[3];
    const float* b1 = (const float*)d_in[4];
    const float* E  = (const float*)d_in[5];
    const float* bn2_gamma = (const float*)d_in[6];
    const float* bn2_beta  = (const float*)d_in[7];
    const float* W2 = (const float*)d_in[8];
    const float* b2 = (const float*)d_in[9];

    float* ws = (float*)d_ws;
    float* Mp  = ws + OFF_MP;
    float* cp  = ws + OFF_CP;
    float* Q   = ws + OFF_Q;
    float* W2T = ws + OFF_W2T;
    float* u   = ws + OFF_U;
    float* cQ  = ws + OFF_CQ;
    int* idx   = (int*)(ws + OFF_IDX);
    float* pval = ws + OFF_PV;
    int* pidx   = (int*)(ws + OFF_PI);
    unsigned short* Ah = (unsigned short*)(ws + OFF_AH);
    unsigned short* Al = (unsigned short*)(ws + OFF_AL);
    unsigned short* Bh = (unsigned short*)(ws + OFF_BH);
    unsigned short* Bl = (unsigned short*)(ws + OFF_BL);
    float* out = (float*)d_out;

    const bool fast = ws_size >= (size_t)TOT_F * 4;

    hipLaunchKernelGGL(zero_out_kernel, dim3(8), dim3(256), 0, stream, out);
    hipLaunchKernelGGL(prep1_kernel, dim3(768), dim3(256), 0, stream,
                       W1, W2, bn1_beta, bn2_gamma, bn2_beta, b2, W2T, u, cQ);
    hipLaunchKernelGGL(prep2_kernel, dim3(512), dim3(256), 0, stream,
                       E, W1, W2T, bn1_gamma, cQ, Mp, Q);
    hipLaunchKernelGGL(prep3_kernel, dim3(8), dim3(256), 0, stream, E, b1, u, cp);
    if (fast) {
        hipLaunchKernelGGL(pack_kernel, dim3(TOK / 32), dim3(256), 0, stream, inputs, Ah, Al, NTA);
        hipLaunchKernelGGL(pack_kernel, dim3(KCB / 32), dim3(256), 0, stream, Mp, Bh, Bl, NTB);
        hipLaunchKernelGGL(score_mfma_kernel, dim3(16, 512), dim3(256), 0, stream,
                           Ah, Al, Bh, Bl, cp, pval, pidx);
        hipLaunchKernelGGL(reduce_idx_kernel, dim3(256), dim3(256), 0, stream, pval, pidx, idx);
    } else {
        hipLaunchKernelGGL(score_argmax_kernel, dim3(512), dim3(256), 0, stream, inputs, Mp, cp, idx);
    }
    hipLaunchKernelGGL(gather_out_kernel, dim3(512), dim3(256), 0, stream, inputs, Q, idx, out);
}

// Round 4
// 405.435 us; speedup vs baseline: 2.5488x; 1.1794x over previous
//
#include <hip/hip_runtime.h>
#include <math.h>
#include <stdint.h>

#define TOK 65536
#define DIN 256
#define EDIM 512
#define KCB 2048
#define NTA 4096        // A m-tiles (65536/16)
#define NTB 128         // B n-tiles (2048/16)

// workspace layout (float offsets), 64-float aligned
#define OFF_MP   0u                     // M' fp32 [2048*256]
#define OFF_CP   524288u                // c' [2048]
#define OFF_Q    526336u                // Q [2048*256]
#define OFF_W2T  1050624u               // W2T [512*256]
#define OFF_U    1181696u               // u [512]
#define OFF_CQ   1182208u               // cQ [256]
#define OFF_PV   1182464u               // partial vals [65536*16]
#define OFF_PI   2231040u               // partial idx [65536*16]
#define OFF_AH   3279616u               // A packed bf16 [8][4096][512]
#define OFF_BH   11668224u              // B packed bf16 [8][128][512]
#define TOT_F    11930368u

typedef short short8 __attribute__((ext_vector_type(8)));
typedef float f32x4 __attribute__((ext_vector_type(4)));

__device__ __forceinline__ unsigned short bf16rne(float x) {
    uint32_t u = __float_as_uint(x);
    u += 0x7fffu + ((u >> 16) & 1u);
    return (unsigned short)(u >> 16);
}

// fused: zero loss scalar + usage bins, then prep1 work.
// blocks 0..511: e -> W2T[e][o], u[e];  512..767: o -> cQ[o]
__global__ void prep1_kernel(const float* __restrict__ W1, const float* __restrict__ W2,
                             const float* __restrict__ bn1_beta, const float* __restrict__ bn2_gamma,
                             const float* __restrict__ bn2_beta, const float* __restrict__ b2,
                             float* __restrict__ W2T, float* __restrict__ u, float* __restrict__ cQ,
                             float* __restrict__ out) {
    __shared__ float red[256];
    const int b = blockIdx.x, t = threadIdx.x;
    const int gid = b * 256 + t;
    if (gid == 0) out[0] = 0.0f;
    if (gid < KCB) out[1 + TOK * DIN + gid] = 0.0f;
    const float s = 1.0f / sqrtf(1.0f + 1e-5f);
    if (b < EDIM) {
        int e = b;
        W2T[e * DIN + t] = bn2_gamma[e] * s * W2[t * EDIM + e];
        float v = bn1_beta[t] * W1[e * DIN + t];
        red[t] = v; __syncthreads();
        for (int off = 128; off; off >>= 1) { if (t < off) red[t] += red[t + off]; __syncthreads(); }
        if (t == 0) u[e] = red[0];
    } else {
        int o = b - EDIM;
        float v = bn2_beta[t] * W2[o * EDIM + t] + bn2_beta[t + 256] * W2[o * EDIM + t + 256];
        red[t] = v; __syncthreads();
        for (int off = 128; off; off >>= 1) { if (t < off) red[t] += red[t + off]; __syncthreads(); }
        if (t == 0) cQ[o] = b2[o] + red[0];
    }
}

// per block: 8 codebook rows -> Mp fp32, Q fp32
__global__ __launch_bounds__(256) void prep2_kernel(const float* __restrict__ E, const float* __restrict__ W1,
                                                    const float* __restrict__ W2T, const float* __restrict__ bn1_gamma,
                                                    const float* __restrict__ cQ,
                                                    float* __restrict__ Mp, float* __restrict__ Q) {
    __shared__ float Elds[EDIM * 8]; // [e][kk] 16 KB
    const int k0 = blockIdx.x * 8, t = threadIdx.x;
    const float4* src = (const float4*)(E + (size_t)k0 * EDIM);
    for (int i = t; i < 1024; i += 256) {
        float4 v = src[i];
        int kk = i >> 7;
        int e = (i & 127) << 2;
        Elds[(e + 0) * 8 + kk] = v.x; Elds[(e + 1) * 8 + kk] = v.y;
        Elds[(e + 2) * 8 + kk] = v.z; Elds[(e + 3) * 8 + kk] = v.w;
    }
    __syncthreads();
    float m[8] = {0, 0, 0, 0, 0, 0, 0, 0};
    float q[8] = {0, 0, 0, 0, 0, 0, 0, 0};
    for (int e = 0; e < EDIM; e++) {
        float w1 = W1[e * DIN + t];
        float w2 = W2T[e * DIN + t];
        float4 e0 = *(const float4*)&Elds[e * 8];
        float4 e1 = *(const float4*)&Elds[e * 8 + 4];
        float ev[8] = {e0.x, e0.y, e0.z, e0.w, e1.x, e1.y, e1.z, e1.w};
#pragma unroll
        for (int i = 0; i < 8; i++) { m[i] += ev[i] * w1; q[i] += ev[i] * w2; }
    }
    const float s = 1.0f / sqrtf(1.0f + 1e-5f);
    const float gs = bn1_gamma[t] * s;
    const float cq = cQ[t];
#pragma unroll
    for (int i = 0; i < 8; i++) {
        Mp[(size_t)(k0 + i) * DIN + t] = gs * m[i];
        Q[(size_t)(k0 + i) * DIN + t] = q[i] + cq;
    }
}

// c'[k] = sum_e E[k][e]*(b1[e]+u[e]) - 0.5*sum_e E[k][e]^2
__global__ void prep3_kernel(const float* __restrict__ E, const float* __restrict__ b1,
                             const float* __restrict__ u, float* __restrict__ cp) {
    int k = blockIdx.x * 256 + threadIdx.x;
    const float4* er = (const float4*)(E + (size_t)k * EDIM);
    float sa = 0.0f, sb = 0.0f;
    for (int i = 0; i < 128; i++) {
        float4 ev = er[i];
        int e = i * 4;
        sa += ev.x * (b1[e] + u[e]) + ev.y * (b1[e + 1] + u[e + 1])
            + ev.z * (b1[e + 2] + u[e + 2]) + ev.w * (b1[e + 3] + u[e + 3]);
        sb += ev.x * ev.x + ev.y * ev.y + ev.z * ev.z + ev.w * ev.w;
    }
    cp[k] = sa - 0.5f * sb;
}

// X[R x 256] fp32 -> bf16 in MFMA fragment-tile order:
// plane kc (0..7), tile tt (16 rows), 1KB block: lane L owns
// X[tt*16 + (L&15)][kc*32 + (L>>4)*8 + 0..7].
__global__ __launch_bounds__(256) void pack_kernel(const float* __restrict__ X,
                                                   unsigned short* __restrict__ Hp, int ntiles) {
    __shared__ __align__(16) unsigned short Hs[32 * 264];
    const int t = threadIdx.x;
    const int r0 = blockIdx.x * 32;
    const float4* src = (const float4*)(X + (size_t)r0 * DIN);
#pragma unroll
    for (int i = 0; i < 8; i++) {
        int id = i * 256 + t;
        int row = id >> 6, c4 = id & 63;
        float4 v = src[id];
        float f[4] = {v.x, v.y, v.z, v.w};
        ushort4 H;
        unsigned short* hp = (unsigned short*)&H;
#pragma unroll
        for (int j = 0; j < 4; j++) hp[j] = bf16rne(f[j]);
        *(ushort4*)&Hs[row * 264 + c4 * 4] = H;
    }
    __syncthreads();
    const int lane = t & 63, w = t >> 6;
#pragma unroll
    for (int q = 0; q < 4; q++) {
        int fb = q * 4 + w;              // 0..15
        int tl = fb >> 3, kc = fb & 7;
        int srow = tl * 16 + (lane & 15);
        int scol = kc * 32 + (lane >> 4) * 8;
        short8 vh = *(const short8*)&Hs[srow * 264 + scol];
        size_t off = ((size_t)kc * ntiles + (r0 >> 4) + tl) * 512 + lane * 8;
        *(short8*)&Hp[off] = vh;
    }
}

// MFMA scorer, direct global->VGPR fragment loads (packed layout == fragment layout).
// No LDS staging, no K-loop barriers. C[128m x 128n], K=256 single-bf16.
// grid (16 nb fastest, 512 m) -> packed B (1 MB) + A tile L2-resident.
__global__ __launch_bounds__(256) void score_mfma_kernel(const unsigned short* __restrict__ Ah,
                                                         const unsigned short* __restrict__ Bh,
                                                         const float* __restrict__ cp,
                                                         float* __restrict__ pval, int* __restrict__ pidx) {
    __shared__ float ev[2 * 128];
    __shared__ int   ei[2 * 128];
    const int t = threadIdx.x, lane = t & 63, w = t >> 6;
    const int wm = w & 1, wn = w >> 1;
    const int nb = blockIdx.x;
    const int m0 = blockIdx.y * 128;
    const int n0 = nb * 128;
    const int amt = (m0 >> 4) + wm * 4;   // wave's first A tile
    const int bnt = nb * 8 + wn * 4;      // wave's first B tile

    const short8* A8 = (const short8*)Ah; // frag = A8[(kc*NTA + tile)*64 + lane]
    const short8* B8 = (const short8*)Bh;

    f32x4 acc[4][4];
#pragma unroll
    for (int i = 0; i < 4; i++)
#pragma unroll
        for (int j = 0; j < 4; j++) acc[i][j] = (f32x4){0.f, 0.f, 0.f, 0.f};

#pragma unroll
    for (int kc = 0; kc < 8; kc++) {
        short8 af[4], bf[4];
#pragma unroll
        for (int mt = 0; mt < 4; mt++)
            af[mt] = A8[((size_t)kc * NTA + amt + mt) * 64 + lane];
#pragma unroll
        for (int nt = 0; nt < 4; nt++)
            bf[nt] = B8[((size_t)kc * NTB + bnt + nt) * 64 + lane];
#pragma unroll
        for (int mt = 0; mt < 4; mt++)
#pragma unroll
            for (int nt = 0; nt < 4; nt++)
                acc[mt][nt] = __builtin_amdgcn_mfma_f32_16x16x32_bf16(af[mt], bf[nt], acc[mt][nt], 0, 0, 0);
    }

    // epilogue: add c', argmax over this block's 128 codes per row
    const int fr = lane & 15;
    const int colb = n0 + wn * 64 + fr;
    float cpv[4];
#pragma unroll
    for (int nt = 0; nt < 4; nt++) cpv[nt] = cp[colb + nt * 16];
#pragma unroll
    for (int mt = 0; mt < 4; mt++) {
#pragma unroll
        for (int r = 0; r < 4; r++) {
            float bv = acc[mt][0][r] + cpv[0];
            int bc = colb;
#pragma unroll
            for (int nt = 1; nt < 4; nt++) {
                float v = acc[mt][nt][r] + cpv[nt];
                if (v > bv) { bv = v; bc = colb + nt * 16; }
            }
#pragma unroll
            for (int xm = 1; xm < 16; xm <<= 1) {
                float ov = __shfl_xor(bv, xm, 64);
                int oc = __shfl_xor(bc, xm, 64);
                if (ov > bv || (ov == bv && oc < bc)) { bv = ov; bc = oc; }
            }
            if (fr == 0) {
                int row = wm * 64 + mt * 16 + ((lane >> 4) << 2) + r;
                ev[wn * 128 + row] = bv;
                ei[wn * 128 + row] = bc;
            }
        }
    }
    __syncthreads();
    if (t < 128) {
        float v0 = ev[t]; int c0 = ei[t];
        float v1 = ev[128 + t]; int c1 = ei[128 + t];
        if (v1 > v0) { v0 = v1; c0 = c1; }   // wn=1 cols strictly higher -> strict >
        pval[(size_t)(m0 + t) * 16 + nb] = v0;
        pidx[(size_t)(m0 + t) * 16 + nb] = c0;
    }
}

// gather: per row, reduce 16 partials in-wave -> k, then Q[k] -> out,
// fused loss reduction + usage histogram.
__global__ __launch_bounds__(256) void gather_out_kernel(const float* __restrict__ flat,
                                                         const float* __restrict__ Q,
                                                         const float* __restrict__ pval,
                                                         const int* __restrict__ pidx,
                                                         float* __restrict__ out) {
    const int t = threadIdx.x;
    const int lane = t & 63;
    const int gw = blockIdx.x * 4 + (t >> 6);
    float lsum = 0.0f;
    for (int r = 0; r < 32; r++) {
        int row = gw * 32 + r;
        // all 64 lanes load the 16 partials (4x replicated), butterfly-reduce
        float v = pval[(size_t)row * 16 + (lane & 15)];
        int c = pidx[(size_t)row * 16 + (lane & 15)];
#pragma unroll
        for (int xm = 1; xm < 16; xm <<= 1) {
            float ov = __shfl_xor(v, xm, 64);
            int oc = __shfl_xor(c, xm, 64);
            if (ov > v || (ov == v && oc < c)) { v = ov; c = oc; }
        }
        int k = c;
        const float* qr = Q + (size_t)k * DIN;
        const float* xr = flat + (size_t)row * DIN;
        float* ob = out + 1 + (size_t)row * DIN;
#pragma unroll
        for (int cc = 0; cc < 4; cc++) {
            int j = lane + 64 * cc;
            float q = qr[j];
            float d = q - xr[j];
            lsum += d * d;
            ob[j] = q;
        }
        if (lane == 0) atomicAdd(out + 1 + TOK * DIN + k, 1.0f / (float)TOK);
    }
#pragma unroll
    for (int off = 32; off; off >>= 1) lsum += __shfl_down(lsum, off, 64);
    if (lane == 0) atomicAdd(out, lsum * (1.25f / (float)((size_t)TOK * DIN)));
}

extern "C" void kernel_launch(void* const* d_in, const int* in_sizes, int n_in,
                              void* d_out, int out_size, void* d_ws, size_t ws_size,
                              hipStream_t stream) {
    const float* inputs = (const float*)d_in[0];
    const float* bn1_gamma = (const float*)d_in[1];
    const float* bn1_beta  = (const float*)d_in[2];
    const float* W1 = (const float*)d_in[3];
    const float* b1 = (const float*)d_in[4];
    const float* E  = (const float*)d_in[5];
    const float* bn2_gamma = (const float*)d_in[6];
    const float* bn2_beta  = (const float*)d_in[7];
    const float* W2 = (const float*)d_in[8];
    const float* b2 = (const float*)d_in[9];

    float* ws = (float*)d_ws;
    float* Mp  = ws + OFF_MP;
    float* cp  = ws + OFF_CP;
    float* Q   = ws + OFF_Q;
    float* W2T = ws + OFF_W2T;
    float* u   = ws + OFF_U;
    float* cQ  = ws + OFF_CQ;
    float* pval = ws + OFF_PV;
    int* pidx   = (int*)(ws + OFF_PI);
    unsigned short* Ah = (unsigned short*)(ws + OFF_AH);
    unsigned short* Bh = (unsigned short*)(ws + OFF_BH);
    float* out = (float*)d_out;

    hipLaunchKernelGGL(prep1_kernel, dim3(768), dim3(256), 0, stream,
                       W1, W2, bn1_beta, bn2_gamma, bn2_beta, b2, W2T, u, cQ, out);
    hipLaunchKernelGGL(prep2_kernel, dim3(256), dim3(256), 0, stream,
                       E, W1, W2T, bn1_gamma, cQ, Mp, Q);
    hipLaunchKernelGGL(prep3_kernel, dim3(8), dim3(256), 0, stream, E, b1, u, cp);
    hipLaunchKernelGGL(pack_kernel, dim3(TOK / 32), dim3(256), 0, stream, inputs, Ah, NTA);
    hipLaunchKernelGGL(pack_kernel, dim3(KCB / 32), dim3(256), 0, stream, Mp, Bh, NTB);
    hipLaunchKernelGGL(score_mfma_kernel, dim3(16, 512), dim3(256), 0, stream,
                       Ah, Bh, cp, pval, pidx);
    hipLaunchKernelGGL(gather_out_kernel, dim3(512), dim3(256), 0, stream,
                       inputs, Q, pval, pidx, out);
}